// Round 1
// 575.662 us; speedup vs baseline: 1.0533x; 1.0533x over previous
//
#include <hip/hip_runtime.h>
#include <hip/hip_bf16.h>
#include <math.h>

#define B_ 16
#define T_ 4096
#define D_ 1024
#define U_ 1024
#define M_ (B_*T_)   // 65536

typedef __attribute__((ext_vector_type(8))) short short8;
typedef __attribute__((ext_vector_type(4))) short short4v;
typedef __attribute__((ext_vector_type(4))) float float4v;

static __device__ __forceinline__ short f2bf(float f) {
    unsigned u = __builtin_bit_cast(unsigned, f);
    u += 0x7FFFu + ((u >> 16) & 1u);   // RNE
    return (short)(u >> 16);
}
static __device__ __forceinline__ float bf2f(short s) {
    unsigned u = ((unsigned)(unsigned short)s) << 16;
    return __builtin_bit_cast(float, u);
}
static __device__ __forceinline__ float fast_tanh(float x) {
    float c = fminf(fmaxf(2.f * x, -30.f), 30.f);
    float t = __expf(c);
    return __fdividef(t - 1.f, t + 1.f);
}

#define GLLDS(GP, LP) __builtin_amdgcn_global_load_lds( \
    (const __attribute__((address_space(1))) void*)(GP), \
    (__attribute__((address_space(3))) void*)(LP), 16, 0, 0)

// ---------------- kernel 1: hb partials, K split 4 ways
__global__ void hb_kernel(const float* __restrict__ h, const float* __restrict__ W1,
                          const float* __restrict__ b1, const float* __restrict__ b2,
                          float* __restrict__ hbp) {
    int x = blockIdx.x;                       // 256
    int kc = x >> 6;                          // 0..3
    int gid = (x & 63) * 256 + threadIdx.x;   // 0..16383
    int b = gid >> 10, u = gid & 1023;
    const float* hr = h + b * D_ + kc * 256;
    const float* w = W1 + (size_t)(kc * 256) * U_ + u;
    float s0 = 0.f, s1 = 0.f, s2 = 0.f, s3 = 0.f;
    for (int k = 0; k < 256; k += 4) {
        s0 += hr[k+0] * w[(size_t)(k+0) * U_];
        s1 += hr[k+1] * w[(size_t)(k+1) * U_];
        s2 += hr[k+2] * w[(size_t)(k+2) * U_];
        s3 += hr[k+3] * w[(size_t)(k+3) * U_];
    }
    float s = ((s0 + s1) + (s2 + s3));
    if (kc == 0) s += b1[u] + b2[u];
    hbp[kc * 16384 + gid] = s;
}

// ---------------- converters
__global__ void convert_enc(const float* __restrict__ enc, short* __restrict__ encbf) {
    size_t g = (size_t)blockIdx.x * 256 + threadIdx.x;
    const float4v* p = (const float4v*)(enc + g * 16);
    float4v f0 = p[0], f1 = p[1], f2 = p[2], f3 = p[3];
    short8 a, b;
    a[0]=f2bf(f0[0]); a[1]=f2bf(f0[1]); a[2]=f2bf(f0[2]); a[3]=f2bf(f0[3]);
    a[4]=f2bf(f1[0]); a[5]=f2bf(f1[1]); a[6]=f2bf(f1[2]); a[7]=f2bf(f1[3]);
    b[0]=f2bf(f2[0]); b[1]=f2bf(f2[1]); b[2]=f2bf(f2[2]); b[3]=f2bf(f2[3]);
    b[4]=f2bf(f3[0]); b[5]=f2bf(f3[1]); b[6]=f2bf(f3[2]); b[7]=f2bf(f3[3]);
    short8* q = (short8*)(encbf + g * 16);
    q[0] = a; q[1] = b;
}

__global__ void convert_w2t(const float* __restrict__ W2, short* __restrict__ W2T) {
    __shared__ short t[64][65];
    int k0 = (blockIdx.x >> 4) * 64, u0 = (blockIdx.x & 15) * 64;
    int tx = threadIdx.x & 63, ty = threadIdx.x >> 6;
    #pragma unroll
    for (int r = 0; r < 16; ++r) {
        int kk = ty * 16 + r;
        t[kk][tx] = f2bf(W2[(size_t)(k0 + kk) * U_ + u0 + tx]);
    }
    __syncthreads();
    #pragma unroll
    for (int r = 0; r < 16; ++r) {
        int uu = ty * 16 + r;
        W2T[(size_t)(u0 + uu) * D_ + k0 + tx] = t[tx][uu];
    }
}

// ---------------- kernel 2: 256x256-tile 8-phase bf16 GEMM + tanh*V epilogue.
// T2 (XOR slot swizzle, both-sides: pre-swizzled global src for global_load_lds +
// swizzled ds_read addr) + T3/T4 (4 phases per BK=64 K-tile, counted vmcnt(6),
// never drained in main loop) + T5 (setprio around MFMA) + T1 (XCD swizzle).
// 8 waves (2M x 4N), per-wave 128x64 output, acc[8][4] f32x4. LDS 128 KiB.
__global__ __launch_bounds__(512, 2) void gemm_score_8ph(
    const short* __restrict__ Abf,   // enc bf16 [M_, D_]
    const short* __restrict__ W2T,   // bf16 [U_, D_]
    const float* __restrict__ hbp,   // [4][B_, U_]
    const float* __restrict__ V,
    float* __restrict__ scorepart)   // [4][M_]
{
    __shared__ __align__(16) short lds[65536];   // A: [0,32768), B: [32768,65536) shorts

    const int tid = threadIdx.x;
    const int g = blockIdx.x;
    const int c = g & 7, q = g >> 3;            // XCD round-robin; 1024 % 8 == 0 -> bijective
    const int ntile = q & 3;                    // 4 ntiles walked consecutively per XCD
    const int mtile = (q >> 2) * 8 + c;
    const int row0 = mtile * 256, n0 = ntile * 256;
    const int bidx = row0 >> 12;                // 256-row tile never crosses batch (4096 % 256 == 0)

    const int lane = tid & 63;
    const int wv = tid >> 6;
    const int wm = wv >> 2, wn = wv & 3;        // 2M x 4N waves
    const int lm = lane & 15, quad = lane >> 4;

    // staging geometry: one GLLDS round = 512 thr x 16B = 64 rows x 128B
    const int srow = tid >> 3;                  // row within 64-row round
    const int lslot = (tid & 7) ^ (srow & 7);   // inverse swizzle on the GLOBAL source
    const short* aS = Abf + (size_t)(row0 + srow) * D_ + lslot * 8;
    const short* bS = W2T + (size_t)(n0  + srow) * D_ + lslot * 8;
    short* aD = lds + tid * 8;                  // linear LDS dest (wave-uniform base + lane*16)
    short* bD = lds + 32768 + tid * 8;

#define STG_A(kt, h, bf) do { \
    GLLDS(aS + (size_t)((h) * 128) * D_ + (kt) * 64,      aD + (bf) * 16384 + (h) * 8192); \
    GLLDS(aS + (size_t)((h) * 128 + 64) * D_ + (kt) * 64, aD + (bf) * 16384 + (h) * 8192 + 4096); \
} while (0)
#define STG_B(kt, h, bf) do { \
    GLLDS(bS + (size_t)((h) * 128) * D_ + (kt) * 64,      bD + (bf) * 16384 + (h) * 8192); \
    GLLDS(bS + (size_t)((h) * 128 + 64) * D_ + (kt) * 64, bD + (bf) * 16384 + (h) * 8192 + 4096); \
} while (0)
#define LDS_RD(off) (*(const short8*)(lds + (off)))
#define MFMA(a, b, c) __builtin_amdgcn_mfma_f32_16x16x32_bf16((a), (b), (c), 0, 0, 0)

    // swizzled read bases: phys_slot = (ks*4+quad) ^ (lm&7); ks=1 flips bit 32 (shorts)
    const int aB0 = (wm * 128 + lm) * 64 + (quad ^ (lm & 7)) * 8;
    const int aB1 = aB0 ^ 32;
    const int bB0 = 32768 + (wn * 64 + lm) * 64 + (quad ^ (lm & 7)) * 8;
    const int bB1 = bB0 ^ 32;

    float4v acc[8][4] = {};
    short8 Af[4][2], Bf[4][2];

    // ---- prologue: tile0 all 4 halves, then tile1 {B-lo, A-lo, B-hi} (3 halves = 6 loads in flight)
    STG_A(0, 0, 0); STG_A(0, 1, 0); STG_B(0, 0, 0); STG_B(0, 1, 0);
    STG_B(1, 0, 1); STG_A(1, 0, 1); STG_B(1, 1, 1);
    asm volatile("s_waitcnt vmcnt(6)" ::: "memory");
    __builtin_amdgcn_s_barrier();
    __builtin_amdgcn_sched_barrier(0);

    for (int t = 0; t < 16; ++t) {
        const int buf = t & 1;
        const int ab = buf * 16384;
        // ---------- phase 0: read A-lo frags + B-lo frags (12 ds_read), stage A-hi(t+1)
        #pragma unroll
        for (int mi = 0; mi < 4; ++mi) {
            Af[mi][0] = LDS_RD(ab + aB0 + mi * 1024);
            Af[mi][1] = LDS_RD(ab + aB1 + mi * 1024);
        }
        #pragma unroll
        for (int ni = 0; ni < 2; ++ni) {
            Bf[ni][0] = LDS_RD(ab + bB0 + ni * 1024);
            Bf[ni][1] = LDS_RD(ab + bB1 + ni * 1024);
        }
        if (t < 15) STG_A(t + 1, 1, (t + 1) & 1);
        __builtin_amdgcn_s_barrier();
        __builtin_amdgcn_s_setprio(1);
        #pragma unroll
        for (int mi = 0; mi < 4; ++mi)
            #pragma unroll
            for (int ni = 0; ni < 2; ++ni) {
                acc[mi][ni] = MFMA(Af[mi][0], Bf[ni][0], acc[mi][ni]);
                acc[mi][ni] = MFMA(Af[mi][1], Bf[ni][1], acc[mi][ni]);
            }
        __builtin_amdgcn_s_setprio(0);
        __builtin_amdgcn_s_barrier();
        // ---------- phase 1: read B-hi frags (4 ds_read); B fully consumed after this phase
        #pragma unroll
        for (int ni = 0; ni < 2; ++ni) {
            Bf[2 + ni][0] = LDS_RD(ab + bB0 + (2 + ni) * 1024);
            Bf[2 + ni][1] = LDS_RD(ab + bB1 + (2 + ni) * 1024);
        }
        __builtin_amdgcn_s_barrier();
        __builtin_amdgcn_s_setprio(1);
        #pragma unroll
        for (int mi = 0; mi < 4; ++mi)
            #pragma unroll
            for (int ni = 0; ni < 2; ++ni) {
                acc[mi][2 + ni] = MFMA(Af[mi][0], Bf[2 + ni][0], acc[mi][2 + ni]);
                acc[mi][2 + ni] = MFMA(Af[mi][1], Bf[2 + ni][1], acc[mi][2 + ni]);
            }
        __builtin_amdgcn_s_setprio(0);
        __builtin_amdgcn_s_barrier();
        // ---------- phase 2: read A-hi frags (8 ds_read; A consumed after), stage B-lo(t+2)
        #pragma unroll
        for (int mi = 0; mi < 4; ++mi) {
            Af[mi][0] = LDS_RD(ab + aB0 + 4096 + mi * 1024);
            Af[mi][1] = LDS_RD(ab + aB1 + 4096 + mi * 1024);
        }
        if (t < 14) STG_B(t + 2, 0, buf);
        __builtin_amdgcn_s_barrier();
        __builtin_amdgcn_s_setprio(1);
        #pragma unroll
        for (int mi = 0; mi < 4; ++mi)
            #pragma unroll
            for (int ni = 0; ni < 2; ++ni) {
                acc[4 + mi][ni] = MFMA(Af[mi][0], Bf[ni][0], acc[4 + mi][ni]);
                acc[4 + mi][ni] = MFMA(Af[mi][1], Bf[ni][1], acc[4 + mi][ni]);
            }
        __builtin_amdgcn_s_setprio(0);
        __builtin_amdgcn_s_barrier();
        // ---------- phase 3: no reads; stage A-lo(t+2)+B-hi(t+2); counted vmcnt at tile boundary
        if (t < 14) { STG_A(t + 2, 0, buf); STG_B(t + 2, 1, buf); }
        __builtin_amdgcn_s_barrier();
        __builtin_amdgcn_s_setprio(1);
        #pragma unroll
        for (int mi = 0; mi < 4; ++mi)
            #pragma unroll
            for (int ni = 0; ni < 2; ++ni) {
                acc[4 + mi][2 + ni] = MFMA(Af[mi][0], Bf[2 + ni][0], acc[4 + mi][2 + ni]);
                acc[4 + mi][2 + ni] = MFMA(Af[mi][1], Bf[2 + ni][1], acc[4 + mi][2 + ni]);
            }
        __builtin_amdgcn_s_setprio(0);
        if (t < 14)      { asm volatile("s_waitcnt vmcnt(6)" ::: "memory"); }
        else if (t == 14){ asm volatile("s_waitcnt vmcnt(0)" ::: "memory"); }
        __builtin_amdgcn_s_barrier();
        __builtin_amdgcn_sched_barrier(0);
    }

    // ---------- epilogue: score = sum_u tanh(acc + hb) * V over this block's 256 u's
    float* sbuf = (float*)lds;                  // [4][256] floats; LDS reads all drained
    float hbv[4], Vv[4];
    #pragma unroll
    for (int ni = 0; ni < 4; ++ni) {
        int U = n0 + wn * 64 + ni * 16 + lm;
        int o = bidx * U_ + U;
        hbv[ni] = hbp[o] + hbp[16384 + o] + hbp[32768 + o] + hbp[49152 + o];
        Vv[ni]  = V[U];
    }
    #pragma unroll
    for (int mi = 0; mi < 8; ++mi) {
        #pragma unroll
        for (int r = 0; r < 4; ++r) {
            float s = 0.f;
            #pragma unroll
            for (int ni = 0; ni < 4; ++ni)
                s += fast_tanh(acc[mi][ni][r] + hbv[ni]) * Vv[ni];
            #pragma unroll
            for (int off = 1; off < 16; off <<= 1)
                s += __shfl_xor(s, off, 64);
            if (lm == 0)
                sbuf[wn * 256 + wm * 128 + mi * 16 + quad * 4 + r] = s;
        }
    }
    __syncthreads();
    if (tid < 256)
        scorepart[(size_t)ntile * M_ + row0 + tid] =
            sbuf[tid] + sbuf[256 + tid] + sbuf[512 + tid] + sbuf[768 + tid];
}

// ---------------- kernel 3: per-batch softmax over T (1024 threads)
__global__ __launch_bounds__(1024) void softmax_kernel(
        const float* __restrict__ scorepart,
        const float* __restrict__ bv,
        float* __restrict__ out_attn) {
    __shared__ float sm[T_];
    __shared__ float redm[16];
    __shared__ float reds[16];
    int b = blockIdx.x, tid = threadIdx.x;   // 0..1023
    int wv = tid >> 6;
    float bvv = bv[0];
    float lmax = -1e30f;
    #pragma unroll
    for (int i = 0; i < 4; ++i) {
        int t = tid + i * 1024;
        float s = bvv;
        #pragma unroll
        for (int p = 0; p < 4; ++p) s += scorepart[(size_t)p * M_ + b * T_ + t];
        sm[t] = s;
        lmax = fmaxf(lmax, s);
    }
    #pragma unroll
    for (int off = 1; off < 64; off <<= 1) lmax = fmaxf(lmax, __shfl_xor(lmax, off, 64));
    if ((tid & 63) == 0) redm[wv] = lmax;
    __syncthreads();
    float m = redm[0];
    #pragma unroll
    for (int j = 1; j < 16; ++j) m = fmaxf(m, redm[j]);
    float lsum = 0.f;
    #pragma unroll
    for (int i = 0; i < 4; ++i) {
        int t = tid + i * 1024;
        float e = __expf(sm[t] - m);
        sm[t] = e;
        lsum += e;
    }
    #pragma unroll
    for (int off = 1; off < 64; off <<= 1) lsum += __shfl_xor(lsum, off, 64);
    if ((tid & 63) == 0) reds[wv] = lsum;
    __syncthreads();
    float tot = 0.f;
    #pragma unroll
    for (int j = 0; j < 16; ++j) tot += reds[j];
    float rinv = 1.f / tot;
    #pragma unroll
    for (int i = 0; i < 4; ++i) {
        int t = tid + i * 1024;
        out_attn[b * T_ + t] = sm[t] * rinv;
    }
}

// ---------------- kernel 4: context partials, 512 blocks x 128-row chunks
__global__ void ctx_part_bf(const short* __restrict__ encbf,
                            const float* __restrict__ attn,
                            float* __restrict__ part) {   // [512][1024], aliases scorepart region
    __shared__ float wsm[128];
    int x = blockIdx.x;               // x = tc*16 + b, tc 0..31
    int b = x & 15, tc = x >> 4;
    int tid = threadIdx.x;            // 0..255
    if (tid < 128) wsm[tid] = attn[b * T_ + tc * 128 + tid];
    __syncthreads();
    const short* e0 = encbf + (size_t)(b * T_ + tc * 128) * D_ + tid * 4;
    float4v acc = {};
    for (int t = 0; t < 128; ++t) {
        short4v v = *(const short4v*)(e0 + (size_t)t * D_);
        float w = wsm[t];
        acc[0] += w * bf2f(v[0]);
        acc[1] += w * bf2f(v[1]);
        acc[2] += w * bf2f(v[2]);
        acc[3] += w * bf2f(v[3]);
    }
    *(float4v*)(part + (size_t)x * 1024 + tid * 4) = acc;
}

// ---------------- kernel 5: reduce context partials (32 per (b,d))
__global__ void ctx_reduce_kernel(const float* __restrict__ part, float* __restrict__ ctx) {
    int gid = blockIdx.x * 256 + threadIdx.x;   // 0..16383
    int b = gid >> 10, d = gid & 1023;
    float s = 0.f;
    #pragma unroll
    for (int tc = 0; tc < 32; ++tc) s += part[(size_t)(tc * 16 + b) * 1024 + d];
    ctx[gid] = s;
}

extern "C" void kernel_launch(void* const* d_in, const int* in_sizes, int n_in,
                              void* d_out, int out_size, void* d_ws, size_t ws_size,
                              hipStream_t stream) {
    const float* h   = (const float*)d_in[0];
    const float* enc = (const float*)d_in[1];
    const float* W1  = (const float*)d_in[2];
    const float* b1  = (const float*)d_in[3];
    const float* W2  = (const float*)d_in[4];
    const float* b2  = (const float*)d_in[5];
    const float* V   = (const float*)d_in[6];
    const float* bv  = (const float*)d_in[7];
    float* out = (float*)d_out;                 // [0,16384) context, [16384,81920) attn
    float* ws  = (float*)d_ws;

    float* hbp       = ws;                      // 4*16384 floats (256 KB)
    float* scorepart = ws + 65536;              // [4][M_] floats (1 MB used of 2 MB slot)
    float* ctxpart   = scorepart;               // ALIAS: reused after softmax consumes it
    short* W2T   = (short*)(ws + 65536 + 524288);          // 2 MB
    short* encbf = (short*)((char*)W2T + (size_t)U_ * D_ * 2);  // 128 MB

    hb_kernel<<<256, 256, 0, stream>>>(h, W1, b1, b2, hbp);
    convert_enc<<<16384, 256, 0, stream>>>(enc, encbf);
    convert_w2t<<<256, 256, 0, stream>>>(W2, W2T);
    gemm_score_8ph<<<1024, 512, 0, stream>>>(encbf, W2T, hbp, V, scorepart);
    softmax_kernel<<<16, 1024, 0, stream>>>(scorepart, bv, out + 16384);
    ctx_part_bf<<<512, 256, 0, stream>>>(encbf, out + 16384, ctxpart);
    ctx_reduce_kernel<<<64, 256, 0, stream>>>(ctxpart, out);
}

// Round 3
// 559.321 us; speedup vs baseline: 1.0841x; 1.0292x over previous
//
#include <hip/hip_runtime.h>
#include <hip/hip_bf16.h>
#include <math.h>

#define B_ 16
#define T_ 4096
#define D_ 1024
#define U_ 1024
#define M_ (B_*T_)   // 65536

typedef __attribute__((ext_vector_type(8))) short short8;
typedef __attribute__((ext_vector_type(4))) short short4v;
typedef __attribute__((ext_vector_type(4))) float float4v;

static __device__ __forceinline__ short f2bf(float f) {
    unsigned u = __builtin_bit_cast(unsigned, f);
    u += 0x7FFFu + ((u >> 16) & 1u);   // RNE
    return (short)(u >> 16);
}
static __device__ __forceinline__ float bf2f(short s) {
    unsigned u = ((unsigned)(unsigned short)s) << 16;
    return __builtin_bit_cast(float, u);
}
static __device__ __forceinline__ float fast_tanh(float x) {
    float c = fminf(fmaxf(2.f * x, -30.f), 30.f);
    float t = __expf(c);
    return __fdividef(t - 1.f, t + 1.f);
}

#define GLLDS(GP, LP) __builtin_amdgcn_global_load_lds( \
    (const __attribute__((address_space(1))) void*)(GP), \
    (__attribute__((address_space(3))) void*)(LP), 16, 0, 0)

// ---------------- kernel 1 (fused prep): hb partials + W2 transpose/convert + enc convert
// blocks [0,256): hb, [256,512): w2t, [512,16896): enc. All independent -> one dispatch
// overlaps them instead of stream-serializing 3 launches.
__global__ void prep_fused(const float* __restrict__ h, const float* __restrict__ W1,
                           const float* __restrict__ b1, const float* __restrict__ b2,
                           const float* __restrict__ W2, const float* __restrict__ enc,
                           float* __restrict__ hbp, short* __restrict__ W2T,
                           short* __restrict__ encbf) {
    int bx = blockIdx.x;
    if (bx >= 512) {
        // ---- convert_enc
        size_t g = (size_t)(bx - 512) * 256 + threadIdx.x;
        const float4v* p = (const float4v*)(enc + g * 16);
        float4v f0 = p[0], f1 = p[1], f2 = p[2], f3 = p[3];
        short8 a, b;
        a[0]=f2bf(f0[0]); a[1]=f2bf(f0[1]); a[2]=f2bf(f0[2]); a[3]=f2bf(f0[3]);
        a[4]=f2bf(f1[0]); a[5]=f2bf(f1[1]); a[6]=f2bf(f1[2]); a[7]=f2bf(f1[3]);
        b[0]=f2bf(f2[0]); b[1]=f2bf(f2[1]); b[2]=f2bf(f2[2]); b[3]=f2bf(f2[3]);
        b[4]=f2bf(f3[0]); b[5]=f2bf(f3[1]); b[6]=f2bf(f3[2]); b[7]=f2bf(f3[3]);
        short8* q = (short8*)(encbf + g * 16);
        q[0] = a; q[1] = b;
    } else if (bx < 256) {
        // ---- hb partials, K split 4 ways
        int kc = bx >> 6;
        int gid = (bx & 63) * 256 + threadIdx.x;
        int b = gid >> 10, u = gid & 1023;
        const float* hr = h + b * D_ + kc * 256;
        const float* w = W1 + (size_t)(kc * 256) * U_ + u;
        float s0 = 0.f, s1 = 0.f, s2 = 0.f, s3 = 0.f;
        for (int k = 0; k < 256; k += 4) {
            s0 += hr[k+0] * w[(size_t)(k+0) * U_];
            s1 += hr[k+1] * w[(size_t)(k+1) * U_];
            s2 += hr[k+2] * w[(size_t)(k+2) * U_];
            s3 += hr[k+3] * w[(size_t)(k+3) * U_];
        }
        float s = ((s0 + s1) + (s2 + s3));
        if (kc == 0) s += b1[u] + b2[u];
        hbp[kc * 16384 + gid] = s;
    } else {
        // ---- convert_w2t (transpose to [U][D])
        __shared__ short t[64][65];
        int x = bx - 256;
        int k0 = (x >> 4) * 64, u0 = (x & 15) * 64;
        int tx = threadIdx.x & 63, ty = threadIdx.x >> 6;
        #pragma unroll
        for (int r = 0; r < 16; ++r) {
            int kk = ty * 16 + r;
            t[kk][tx] = f2bf(W2[(size_t)(k0 + kk) * U_ + u0 + tx]);
        }
        __syncthreads();
        #pragma unroll
        for (int r = 0; r < 16; ++r) {
            int uu = ty * 16 + r;
            W2T[(size_t)(u0 + uu) * D_ + k0 + tx] = t[tx][uu];
        }
    }
}

// ---------------- kernel 2: 256x256-tile 8-phase bf16 GEMM + tanh*V epilogue.
// VERBATIM round-1 kernel (verified 180.8us, absmax 4.9e-4) -- serves as the
// within-run control for this round's fusion changes.
__global__ __launch_bounds__(512, 2) void gemm_score_8ph(
    const short* __restrict__ Abf,   // enc bf16 [M_, D_]
    const short* __restrict__ W2T,   // bf16 [U_, D_]
    const float* __restrict__ hbp,   // [4][B_, U_]
    const float* __restrict__ V,
    float* __restrict__ scorepart)   // [4][M_]
{
    __shared__ __align__(16) short lds[65536];   // A: [0,32768), B: [32768,65536) shorts

    const int tid = threadIdx.x;
    const int g = blockIdx.x;
    const int c = g & 7, q = g >> 3;            // XCD round-robin; 1024 % 8 == 0 -> bijective
    const int ntile = q & 3;                    // 4 ntiles walked consecutively per XCD
    const int mtile = (q >> 2) * 8 + c;
    const int row0 = mtile * 256, n0 = ntile * 256;
    const int bidx = row0 >> 12;                // 256-row tile never crosses batch (4096 % 256 == 0)

    const int lane = tid & 63;
    const int wv = tid >> 6;
    const int wm = wv >> 2, wn = wv & 3;        // 2M x 4N waves
    const int lm = lane & 15, quad = lane >> 4;

    // staging geometry: one GLLDS round = 512 thr x 16B = 64 rows x 128B
    const int srow = tid >> 3;                  // row within 64-row round
    const int lslot = (tid & 7) ^ (srow & 7);   // inverse swizzle on the GLOBAL source
    const short* aS = Abf + (size_t)(row0 + srow) * D_ + lslot * 8;
    const short* bS = W2T + (size_t)(n0  + srow) * D_ + lslot * 8;
    short* aD = lds + tid * 8;                  // linear LDS dest (wave-uniform base + lane*16)
    short* bD = lds + 32768 + tid * 8;

#define STG_A(kt, h, bf) do { \
    GLLDS(aS + (size_t)((h) * 128) * D_ + (kt) * 64,      aD + (bf) * 16384 + (h) * 8192); \
    GLLDS(aS + (size_t)((h) * 128 + 64) * D_ + (kt) * 64, aD + (bf) * 16384 + (h) * 8192 + 4096); \
} while (0)
#define STG_B(kt, h, bf) do { \
    GLLDS(bS + (size_t)((h) * 128) * D_ + (kt) * 64,      bD + (bf) * 16384 + (h) * 8192); \
    GLLDS(bS + (size_t)((h) * 128 + 64) * D_ + (kt) * 64, bD + (bf) * 16384 + (h) * 8192 + 4096); \
} while (0)
#define LDS_RD(off) (*(const short8*)(lds + (off)))
#define MFMA(a, b, c) __builtin_amdgcn_mfma_f32_16x16x32_bf16((a), (b), (c), 0, 0, 0)

    // swizzled read bases: phys_slot = (ks*4+quad) ^ (lm&7); ks=1 flips bit 32 (shorts)
    const int aB0 = (wm * 128 + lm) * 64 + (quad ^ (lm & 7)) * 8;
    const int aB1 = aB0 ^ 32;
    const int bB0 = 32768 + (wn * 64 + lm) * 64 + (quad ^ (lm & 7)) * 8;
    const int bB1 = bB0 ^ 32;

    float4v acc[8][4] = {};
    short8 Af[4][2], Bf[4][2];

    // ---- prologue: tile0 all 4 halves, then tile1 {B-lo, A-lo, B-hi} (3 halves = 6 loads in flight)
    STG_A(0, 0, 0); STG_A(0, 1, 0); STG_B(0, 0, 0); STG_B(0, 1, 0);
    STG_B(1, 0, 1); STG_A(1, 0, 1); STG_B(1, 1, 1);
    asm volatile("s_waitcnt vmcnt(6)" ::: "memory");
    __builtin_amdgcn_s_barrier();
    __builtin_amdgcn_sched_barrier(0);

    for (int t = 0; t < 16; ++t) {
        const int buf = t & 1;
        const int ab = buf * 16384;
        // ---------- phase 0: read A-lo frags + B-lo frags (12 ds_read), stage A-hi(t+1)
        #pragma unroll
        for (int mi = 0; mi < 4; ++mi) {
            Af[mi][0] = LDS_RD(ab + aB0 + mi * 1024);
            Af[mi][1] = LDS_RD(ab + aB1 + mi * 1024);
        }
        #pragma unroll
        for (int ni = 0; ni < 2; ++ni) {
            Bf[ni][0] = LDS_RD(ab + bB0 + ni * 1024);
            Bf[ni][1] = LDS_RD(ab + bB1 + ni * 1024);
        }
        if (t < 15) STG_A(t + 1, 1, (t + 1) & 1);
        __builtin_amdgcn_s_barrier();
        __builtin_amdgcn_s_setprio(1);
        #pragma unroll
        for (int mi = 0; mi < 4; ++mi)
            #pragma unroll
            for (int ni = 0; ni < 2; ++ni) {
                acc[mi][ni] = MFMA(Af[mi][0], Bf[ni][0], acc[mi][ni]);
                acc[mi][ni] = MFMA(Af[mi][1], Bf[ni][1], acc[mi][ni]);
            }
        __builtin_amdgcn_s_setprio(0);
        __builtin_amdgcn_s_barrier();
        // ---------- phase 1: read B-hi frags (4 ds_read); B fully consumed after this phase
        #pragma unroll
        for (int ni = 0; ni < 2; ++ni) {
            Bf[2 + ni][0] = LDS_RD(ab + bB0 + (2 + ni) * 1024);
            Bf[2 + ni][1] = LDS_RD(ab + bB1 + (2 + ni) * 1024);
        }
        __builtin_amdgcn_s_barrier();
        __builtin_amdgcn_s_setprio(1);
        #pragma unroll
        for (int mi = 0; mi < 4; ++mi)
            #pragma unroll
            for (int ni = 0; ni < 2; ++ni) {
                acc[mi][2 + ni] = MFMA(Af[mi][0], Bf[2 + ni][0], acc[mi][2 + ni]);
                acc[mi][2 + ni] = MFMA(Af[mi][1], Bf[2 + ni][1], acc[mi][2 + ni]);
            }
        __builtin_amdgcn_s_setprio(0);
        __builtin_amdgcn_s_barrier();
        // ---------- phase 2: read A-hi frags (8 ds_read; A consumed after), stage B-lo(t+2)
        #pragma unroll
        for (int mi = 0; mi < 4; ++mi) {
            Af[mi][0] = LDS_RD(ab + aB0 + 4096 + mi * 1024);
            Af[mi][1] = LDS_RD(ab + aB1 + 4096 + mi * 1024);
        }
        if (t < 14) STG_B(t + 2, 0, buf);
        __builtin_amdgcn_s_barrier();
        __builtin_amdgcn_s_setprio(1);
        #pragma unroll
        for (int mi = 0; mi < 4; ++mi)
            #pragma unroll
            for (int ni = 0; ni < 2; ++ni) {
                acc[4 + mi][ni] = MFMA(Af[mi][0], Bf[ni][0], acc[4 + mi][ni]);
                acc[4 + mi][ni] = MFMA(Af[mi][1], Bf[ni][1], acc[4 + mi][ni]);
            }
        __builtin_amdgcn_s_setprio(0);
        __builtin_amdgcn_s_barrier();
        // ---------- phase 3: no reads; stage A-lo(t+2)+B-hi(t+2); counted vmcnt at tile boundary
        if (t < 14) { STG_A(t + 2, 0, buf); STG_B(t + 2, 1, buf); }
        __builtin_amdgcn_s_barrier();
        __builtin_amdgcn_s_setprio(1);
        #pragma unroll
        for (int mi = 0; mi < 4; ++mi)
            #pragma unroll
            for (int ni = 0; ni < 2; ++ni) {
                acc[4 + mi][2 + ni] = MFMA(Af[mi][0], Bf[2 + ni][0], acc[4 + mi][2 + ni]);
                acc[4 + mi][2 + ni] = MFMA(Af[mi][1], Bf[2 + ni][1], acc[4 + mi][2 + ni]);
            }
        __builtin_amdgcn_s_setprio(0);
        if (t < 14)      { asm volatile("s_waitcnt vmcnt(6)" ::: "memory"); }
        else if (t == 14){ asm volatile("s_waitcnt vmcnt(0)" ::: "memory"); }
        __builtin_amdgcn_s_barrier();
        __builtin_amdgcn_sched_barrier(0);
    }

    // ---------- epilogue: score = sum_u tanh(acc + hb) * V over this block's 256 u's
    float* sbuf = (float*)lds;                  // [4][256] floats; LDS reads all drained
    float hbv[4], Vv[4];
    #pragma unroll
    for (int ni = 0; ni < 4; ++ni) {
        int U = n0 + wn * 64 + ni * 16 + lm;
        int o = bidx * U_ + U;
        hbv[ni] = hbp[o] + hbp[16384 + o] + hbp[32768 + o] + hbp[49152 + o];
        Vv[ni]  = V[U];
    }
    #pragma unroll
    for (int mi = 0; mi < 8; ++mi) {
        #pragma unroll
        for (int r = 0; r < 4; ++r) {
            float s = 0.f;
            #pragma unroll
            for (int ni = 0; ni < 4; ++ni)
                s += fast_tanh(acc[mi][ni][r] + hbv[ni]) * Vv[ni];
            #pragma unroll
            for (int off = 1; off < 16; off <<= 1)
                s += __shfl_xor(s, off, 64);
            if (lm == 0)
                sbuf[wn * 256 + wm * 128 + mi * 16 + quad * 4 + r] = s;
        }
    }
    __syncthreads();
    if (tid < 256)
        scorepart[(size_t)ntile * M_ + row0 + tid] =
            sbuf[tid] + sbuf[256 + tid] + sbuf[512 + tid] + sbuf[768 + tid];
}

// ---------------- kernel 3: fused softmax + context partials.
// Each (b,tc) block recomputes batch-b softmax stats from scorepart (bitwise identical
// reduction across the 32 blocks of a batch -> deterministic attn), writes its 128 attn
// values, then accumulates the weighted encoder sum with 16B/lane loads.
// part MUST NOT alias scorepart (other blocks still reading it) -> lives in dead W2T.
__global__ __launch_bounds__(256) void ctx_softmax(
        const float* __restrict__ scorepart,
        const float* __restrict__ bv,
        const short* __restrict__ encbf,
        float* __restrict__ out_attn,
        float* __restrict__ part)    // [512][1024] (in dead W2T region)
{
    __shared__ float sm[T_];          // 16 KB
    __shared__ float wsm[128];
    __shared__ float lacc[1024];
    __shared__ float red[8];
    const int x = blockIdx.x, tid = threadIdx.x;   // 0..255
    const int b = x & 15, tc = x >> 4;
    const int wvi = tid >> 6;
    const float bv0 = bv[0];
    float lmax = -1e30f;
    #pragma unroll
    for (int i = 0; i < 16; ++i) {
        int t = tid + i * 256;
        const float* sp = scorepart + (size_t)b * T_ + t;
        float s = bv0 + sp[0] + sp[M_] + sp[2 * (size_t)M_] + sp[3 * (size_t)M_];
        sm[t] = s;
        lmax = fmaxf(lmax, s);
    }
    #pragma unroll
    for (int off = 1; off < 64; off <<= 1) lmax = fmaxf(lmax, __shfl_xor(lmax, off, 64));
    if ((tid & 63) == 0) red[wvi] = lmax;
    __syncthreads();
    const float m = fmaxf(fmaxf(red[0], red[1]), fmaxf(red[2], red[3]));
    float lsum = 0.f;
    #pragma unroll
    for (int i = 0; i < 16; ++i) lsum += __expf(sm[tid + i * 256] - m);
    #pragma unroll
    for (int off = 1; off < 64; off <<= 1) lsum += __shfl_xor(lsum, off, 64);
    if ((tid & 63) == 0) red[4 + wvi] = lsum;
    __syncthreads();
    const float tot = (red[4] + red[5]) + (red[6] + red[7]);
    const float rinv = 1.f / tot;
    // own 128 rows: attn out + LDS weights
    if ((tid >> 7) == (tc & 1)) {
        int j = tid & 127;
        int t = tc * 128 + j;
        float w = __expf(sm[t] - m) * rinv;
        wsm[j] = w;
        out_attn[b * T_ + t] = w;
    }
    __syncthreads();
    // weighted sum over 128 rows, 2 rows/iter (parity split), 16B loads
    const int par = tid >> 7;
    const int d0 = (tid & 127) * 8;
    const short* e0 = encbf + (size_t)(b * T_ + tc * 128 + par) * D_ + d0;
    float4v a0 = {}, a1 = {};
    #pragma unroll 4
    for (int it = 0; it < 64; ++it) {
        short8 v = *(const short8*)(e0 + (size_t)it * 2 * D_);
        float w = wsm[it * 2 + par];
        a0[0] += w * bf2f(v[0]); a0[1] += w * bf2f(v[1]);
        a0[2] += w * bf2f(v[2]); a0[3] += w * bf2f(v[3]);
        a1[0] += w * bf2f(v[4]); a1[1] += w * bf2f(v[5]);
        a1[2] += w * bf2f(v[6]); a1[3] += w * bf2f(v[7]);
    }
    if (par) {
        *(float4v*)(lacc + (tid & 127) * 8)     = a0;
        *(float4v*)(lacc + (tid & 127) * 8 + 4) = a1;
    }
    __syncthreads();
    if (!par) {
        const float* l = lacc + tid * 8;
        a0[0] += l[0]; a0[1] += l[1]; a0[2] += l[2]; a0[3] += l[3];
        a1[0] += l[4]; a1[1] += l[5]; a1[2] += l[6]; a1[3] += l[7];
        float4v* pp = (float4v*)(part + (size_t)x * 1024 + tid * 8);
        pp[0] = a0; pp[1] = a1;
    }
}

// ---------------- kernel 4: reduce context partials (32 per (b,d))
__global__ void ctx_reduce_kernel(const float* __restrict__ part, float* __restrict__ ctx) {
    int gid = blockIdx.x * 256 + threadIdx.x;   // 0..16383
    int b = gid >> 10, d = gid & 1023;
    float s = 0.f;
    #pragma unroll
    for (int tc = 0; tc < 32; ++tc) s += part[(size_t)(tc * 16 + b) * 1024 + d];
    ctx[gid] = s;
}

extern "C" void kernel_launch(void* const* d_in, const int* in_sizes, int n_in,
                              void* d_out, int out_size, void* d_ws, size_t ws_size,
                              hipStream_t stream) {
    const float* h   = (const float*)d_in[0];
    const float* enc = (const float*)d_in[1];
    const float* W1  = (const float*)d_in[2];
    const float* b1  = (const float*)d_in[3];
    const float* W2  = (const float*)d_in[4];
    const float* b2  = (const float*)d_in[5];
    const float* V   = (const float*)d_in[6];
    const float* bv  = (const float*)d_in[7];
    float* out = (float*)d_out;                 // [0,16384) context, [16384,81920) attn
    float* ws  = (float*)d_ws;

    float* hbp       = ws;                      // 4*16384 floats (256 KB)
    float* scorepart = ws + 65536;              // [4][M_] floats (1 MB of 2 MB slot)
    short* W2T   = (short*)(ws + 65536 + 524288);          // 2 MB
    float* ctxpart   = (float*)W2T;             // ALIAS: W2T dead after gemm; scorepart stays live
    short* encbf = (short*)((char*)W2T + (size_t)U_ * D_ * 2);  // 128 MB

    prep_fused<<<16896, 256, 0, stream>>>(h, W1, b1, b2, W2, enc, hbp, W2T, encbf);
    gemm_score_8ph<<<1024, 512, 0, stream>>>(encbf, W2T, hbp, V, scorepart);
    ctx_softmax<<<512, 256, 0, stream>>>(scorepart, bv, encbf, out + 16384, ctxpart);
    ctx_reduce_kernel<<<64, 256, 0, stream>>>(ctxpart, out);
}